// Round 21
// baseline (155.158 us; speedup 1.0000x reference)
//
#include <hip/hip_runtime.h>
#include <stdint.h>

#define BB 4
#define NN 2048
#define FIN 256
#define FOUT 128
#define NH 4
#define NEG_SLOPE 0.2f

typedef short bf16x8 __attribute__((ext_vector_type(8)));
typedef unsigned short u16x8 __attribute__((ext_vector_type(8)));
typedef float f32x4 __attribute__((ext_vector_type(4)));
typedef unsigned long long u64;

__device__ inline float b2f(unsigned short u) {
    union { unsigned int i; float f; } x; x.i = ((unsigned int)u) << 16; return x.f;
}
__device__ inline float asf(unsigned int u) {
    union { unsigned int i; float f; } x; x.i = u; return x.f;
}
__device__ inline unsigned short f2b(float f) {   // fp32 -> bf16 RNE
    union { float f; unsigned int i; } x; x.f = f;
    unsigned int r = x.i + 0x7fffu + ((x.i >> 16) & 1u);
    return (unsigned short)(r >> 16);
}
__device__ inline unsigned short f2b_fast(float f) {  // round-half-up (f >= 0 here)
    union { float f; unsigned int i; } x; x.f = f;
    return (unsigned short)((x.i + 0x8000u) >> 16);
}

// ---------------------------------------------------------------------------
// NOTE (timing model, R5): the harness's workspace poison-fill (~43 µs)
// runs INSIDE the timed window each iteration. Controllable budget = dur - 43.
// NOTE (R2): no cross-block fences. NOTE (R10): no LDS A-tiles — A built in
// fragment registers. NOTE (R16/R17): ERf broadcast needs a BIJECTIVE XOR
// skew. NOTE (R18): with conflicts=0 and VALU halved, k2 stayed 44 µs —
// latency-bound at 2 waves/SIMD (6.6K cyc/iter vs ~1K work). This version:
// B-prefetch one iter ahead + bf16-packed ER (1 ds_read_b128 per j, 32KB).
// ---------------------------------------------------------------------------

// ---------------------------------------------------------------------------
// k0_prep: W fp32 -> bf16 hi/lo split only (mask pack lives in k1).
// ---------------------------------------------------------------------------
__global__ __launch_bounds__(256) void k0_prep(const float* __restrict__ Ww,
                                               unsigned short* __restrict__ Whi,
                                               unsigned short* __restrict__ Wlo) {
    int idx = blockIdx.x * 256 + threadIdx.x;   // 32768 elems
    float v = Ww[idx];
    unsigned short hb = f2b(v);
    Whi[idx] = hb;
    Wlo[idx] = f2b(v - b2f(hb));
}

// ---------------------------------------------------------------------------
// K1 (MFMA): blocks [0,512): Wh tile + WhT/EL tables + PACKED ER (bf16 pair
// per (j,h): u32 = f2b(exp(eR)) | f2b(exp(.2 eR))<<16).
// blocks [512, 512+NN): adj row -> 32 u64 bitmask words (overlaps compute).
// ---------------------------------------------------------------------------
__global__ __launch_bounds__(256) void k1_wh(
    const float* __restrict__ h, const unsigned short* __restrict__ Whi,
    const unsigned short* __restrict__ Wlo, const float* __restrict__ Wb,
    const float* __restrict__ attw, unsigned short* __restrict__ WhT,
    float2* __restrict__ ELpair, unsigned int* __restrict__ ERpk,
    const int* __restrict__ adj, u64* __restrict__ mask) {
    if (blockIdx.x >= BB * NN / 16) {            // ---- mask-pack blocks
        int row = blockIdx.x - BB * NN / 16;
        int wave = threadIdx.x >> 6, lane = threadIdx.x & 63;
        #pragma unroll
        for (int it = 0; it < 8; ++it) {
            int w = it * 4 + wave;
            int j = w * 64 + lane;
            u64 mm = __ballot(adj[(size_t)row * NN + j] != 0);
            if (lane == 0) mask[row * 32 + w] = mm;
        }
        return;
    }
    __shared__ unsigned short Ahi[16][264];
    __shared__ unsigned short Alo[16][264];
    __shared__ float whs[16][132];
    int t = threadIdx.x;
    int b = blockIdx.x >> 7;
    int n0 = (blockIdx.x & 127) * 16;
    {
        int r = t >> 4, c = (t & 15) * 16;
        const float* hp = h + ((size_t)(b * NN + n0 + r)) * FIN + c;
        u16x8 hi0, hi1, lo0, lo1;
        #pragma unroll
        for (int q = 0; q < 4; ++q) {
            float4 v = *(const float4*)(hp + q * 4);
            float vv[4] = {v.x, v.y, v.z, v.w};
            #pragma unroll
            for (int e = 0; e < 4; ++e) {
                int idx = q * 4 + e;
                unsigned short hb = f2b(vv[e]);
                unsigned short lb = f2b(vv[e] - b2f(hb));
                if (idx < 8) { hi0[idx] = (short)hb; lo0[idx] = (short)lb; }
                else         { hi1[idx - 8] = (short)hb; lo1[idx - 8] = (short)lb; }
            }
        }
        *(u16x8*)&Ahi[r][c] = *(u16x8*)&hi0;
        *(u16x8*)&Ahi[r][c + 8] = *(u16x8*)&hi1;
        *(u16x8*)&Alo[r][c] = *(u16x8*)&lo0;
        *(u16x8*)&Alo[r][c + 8] = *(u16x8*)&lo1;
    }
    __syncthreads();
    int lane = t & 63, wv = t >> 6;
    int m = lane & 15, quad = lane >> 4;
    int o0 = wv * 32;
    f32x4 acc0 = {0.f, 0.f, 0.f, 0.f}, acc1 = {0.f, 0.f, 0.f, 0.f};
    const unsigned short* wh0 = Whi + (size_t)(o0 + m) * FIN;
    const unsigned short* wl0 = Wlo + (size_t)(o0 + m) * FIN;
    const unsigned short* wh1 = Whi + (size_t)(o0 + 16 + m) * FIN;
    const unsigned short* wl1 = Wlo + (size_t)(o0 + 16 + m) * FIN;
    #pragma unroll
    for (int ks = 0; ks < 8; ++ks) {
        int ko = ks * 32 + quad * 8;
        bf16x8 ahi = *(bf16x8*)&Ahi[m][ko];
        bf16x8 alo = *(bf16x8*)&Alo[m][ko];
        bf16x8 bh0 = *(const bf16x8*)(wh0 + ko);
        bf16x8 bl0 = *(const bf16x8*)(wl0 + ko);
        bf16x8 bh1 = *(const bf16x8*)(wh1 + ko);
        bf16x8 bl1 = *(const bf16x8*)(wl1 + ko);
        acc0 = __builtin_amdgcn_mfma_f32_16x16x32_bf16(ahi, bh0, acc0, 0, 0, 0);
        acc0 = __builtin_amdgcn_mfma_f32_16x16x32_bf16(ahi, bl0, acc0, 0, 0, 0);
        acc0 = __builtin_amdgcn_mfma_f32_16x16x32_bf16(alo, bh0, acc0, 0, 0, 0);
        acc1 = __builtin_amdgcn_mfma_f32_16x16x32_bf16(ahi, bh1, acc1, 0, 0, 0);
        acc1 = __builtin_amdgcn_mfma_f32_16x16x32_bf16(ahi, bl1, acc1, 0, 0, 0);
        acc1 = __builtin_amdgcn_mfma_f32_16x16x32_bf16(alo, bh1, acc1, 0, 0, 0);
    }
    float bias0 = Wb[o0 + m], bias1 = Wb[o0 + 16 + m];
    #pragma unroll
    for (int reg = 0; reg < 4; ++reg) {
        int row = quad * 4 + reg;
        whs[row][o0 + m] = acc0[reg] + bias0;
        whs[row][o0 + 16 + m] = acc1[reg] + bias1;
    }
    __syncthreads();
    {   // WhT writer: 2 threads per o, 8 n each
        int o = t >> 1, half = t & 1;
        u16x8 v8;
        #pragma unroll
        for (int r = 0; r < 8; ++r) v8[r] = (short)f2b(whs[half * 8 + r][o]);
        *(u16x8*)(WhT + (size_t)(b * FOUT + o) * NN + n0 + half * 8) = v8;
    }
    {   // e-dots + exp tables
        int outi = t >> 1, half = t & 1;
        int i = outi >> 3, d = outi & 7, hh = d & 3, side = d >> 2;
        const float* arow = attw + hh * (2 * FOUT) + side * FOUT + half * 64;
        float s = 0.f;
        #pragma unroll 8
        for (int k = 0; k < 64; ++k) s = fmaf(whs[i][half * 64 + k], arow[k], s);
        s += __shfl_xor(s, 1);
        if (half == 0) {
            float p = __expf(s), n = __expf(NEG_SLOPE * s);
            if (side == 0) {
                ELpair[(size_t)(b * NH + hh) * NN + n0 + i] = make_float2(p, n);
            } else {
                ERpk[((size_t)b * NN + n0 + i) * NH + hh] =
                    (unsigned)f2b(p) | ((unsigned)f2b(n) << 16);
            }
        }
    }
}

// ---------------------------------------------------------------------------
// K2 v6: register-fragment A build; waves = (isub 2) x (kp 4).
// R18 fixes: (1) B-fragments double-buffered one iteration ahead (static
// 2x-unrolled; no runtime-indexed arrays); (2) ER packed bf16-pair in LDS
// (one uint4 = all 4 heads of one j; 32KB), bijective XOR skew
// store g ^ (((g>>3)&3)<<1) / read (jb+e) ^ (quad<<1).
// Denominators via ones-MFMA. Tail: 4-way kp reduce (reuses smem).
// grid (NN/32, BB) = 256 blocks x 512 thr.
// ---------------------------------------------------------------------------
#define K2_STEP(BUF, KSV) do {                                                \
    int ks_ = (KSV);                                                          \
    int jb_ = ks_ * 32 + quad * 8;                                            \
    u64 w64_ = mlds[mr * 33 + (ks_ >> 1)];                                    \
    unsigned mb_ = (unsigned)(w64_ >> (((ks_ & 1) << 5) + (quad << 3))) & 0xFFu; \
    bf16x8 af0, af1, af2, af3;                                                \
    _Pragma("unroll")                                                         \
    for (int e = 0; e < 8; ++e) {                                             \
        uint4 er = erpk4[(jb_ + e) ^ (quad << 1)];                            \
        bool bit = (mb_ >> e) & 1u;                                           \
        float w0 = fmaxf(elp[0] * asf(er.x << 16), eln[0] * asf(er.x & 0xFFFF0000u)); \
        float w1 = fmaxf(elp[1] * asf(er.y << 16), eln[1] * asf(er.y & 0xFFFF0000u)); \
        float w2 = fmaxf(elp[2] * asf(er.z << 16), eln[2] * asf(er.z & 0xFFFF0000u)); \
        float w3 = fmaxf(elp[3] * asf(er.w << 16), eln[3] * asf(er.w & 0xFFFF0000u)); \
        af0[e] = bit ? (short)f2b_fast(w0) : (short)0;                        \
        af1[e] = bit ? (short)f2b_fast(w1) : (short)0;                        \
        af2[e] = bit ? (short)f2b_fast(w2) : (short)0;                        \
        af3[e] = bit ? (short)f2b_fast(w3) : (short)0;                        \
    }                                                                         \
    sacc[0] = __builtin_amdgcn_mfma_f32_16x16x32_bf16(af0, ones, sacc[0], 0, 0, 0); \
    sacc[1] = __builtin_amdgcn_mfma_f32_16x16x32_bf16(af1, ones, sacc[1], 0, 0, 0); \
    sacc[2] = __builtin_amdgcn_mfma_f32_16x16x32_bf16(af2, ones, sacc[2], 0, 0, 0); \
    sacc[3] = __builtin_amdgcn_mfma_f32_16x16x32_bf16(af3, ones, sacc[3], 0, 0, 0); \
    _Pragma("unroll")                                                         \
    for (int f = 0; f < 8; ++f) {                                             \
        acc[f][0] = __builtin_amdgcn_mfma_f32_16x16x32_bf16(af0, BUF[f], acc[f][0], 0, 0, 0); \
        acc[f][1] = __builtin_amdgcn_mfma_f32_16x16x32_bf16(af1, BUF[f], acc[f][1], 0, 0, 0); \
        acc[f][2] = __builtin_amdgcn_mfma_f32_16x16x32_bf16(af2, BUF[f], acc[f][2], 0, 0, 0); \
        acc[f][3] = __builtin_amdgcn_mfma_f32_16x16x32_bf16(af3, BUF[f], acc[f][3], 0, 0, 0); \
    } } while (0)

__global__ __launch_bounds__(512, 2) void k2_reg(
    const unsigned short* __restrict__ WhT, const unsigned int* __restrict__ ERpk,
    const float2* __restrict__ ELpair, const u64* __restrict__ mask,
    float* __restrict__ out) {
    __shared__ char smem[49152 + 1536];          // 49.5 KB
    uint4* erpk4 = (uint4*)smem;                 // [2048] XOR-skewed (32 KB)
    u64* mlds = (u64*)(smem + 32768);            // [32][33] padded (8448 B)
    float* sred = (float*)(smem + 49152);        // [3kp'][2isub][4h][4r][4quad]
    int t = threadIdx.x;
    int b = blockIdx.y, i0 = blockIdx.x * 32;
    int lane = t & 63, wv = t >> 6;
    int m = lane & 15, quad = lane >> 4;
    int isub = wv & 1, kp = wv >> 1;             // kp in 0..3

    {   // stage packed ER for this b (bijective XOR-skewed destination)
        const uint4* src = (const uint4*)ERpk + (size_t)b * NN;
        #pragma unroll
        for (int i = 0; i < 4; ++i) {
            int g = t + i * 512;
            erpk4[g ^ (((g >> 3) & 3) << 1)] = src[g];
        }
    }
    {   // stage masks: 32 rows x 32 words, padded stride 33
        #pragma unroll
        for (int i = 0; i < 2; ++i) {
            int idx = t + i * 512;
            int r = idx >> 5, w = idx & 31;
            mlds[r * 33 + w] = mask[(size_t)(i0 + r) * 32 + w];
        }
    }
    int irow = i0 + isub * 16 + m;               // this lane's A row
    float elp[NH], eln[NH];
    #pragma unroll
    for (int hh = 0; hh < NH; ++hh) {
        float2 e2 = ELpair[(size_t)(b * NH + hh) * NN + irow];
        elp[hh] = e2.x; eln[hh] = e2.y;
    }
    __syncthreads();

    bf16x8 ones;
    #pragma unroll
    for (int e = 0; e < 8; ++e) ones[e] = (short)0x3F80;   // bf16 1.0

    const unsigned short* bp[8];
    #pragma unroll
    for (int f = 0; f < 8; ++f)
        bp[f] = WhT + (size_t)(b * FOUT + f * 16 + m) * NN + kp * 32 + quad * 8;

    f32x4 acc[8][NH];                            // [o-frag f][head h]
    f32x4 sacc[NH];                              // [head h] denominator
    #pragma unroll
    for (int f = 0; f < 8; ++f)
        #pragma unroll
        for (int hh = 0; hh < NH; ++hh) acc[f][hh] = (f32x4){0.f, 0.f, 0.f, 0.f};
    #pragma unroll
    for (int hh = 0; hh < NH; ++hh) sacc[hh] = (f32x4){0.f, 0.f, 0.f, 0.f};

    int mr = isub * 16 + m;                      // local mask row

    // ---- main loop: 16 iters, 2x-unrolled, B double-buffered one iter ahead
    bf16x8 bA[8], bB[8];
    #pragma unroll
    for (int f = 0; f < 8; ++f) { bA[f] = *(const bf16x8*)bp[f]; bp[f] += 128; }
    #pragma unroll 1
    for (int it = 0; it < 16; it += 2) {
        #pragma unroll
        for (int f = 0; f < 8; ++f) { bB[f] = *(const bf16x8*)bp[f]; bp[f] += 128; }
        K2_STEP(bA, (it << 2) | kp);
        if (it + 2 < 16) {
            #pragma unroll
            for (int f = 0; f < 8; ++f) { bA[f] = *(const bf16x8*)bp[f]; bp[f] += 128; }
        }
        K2_STEP(bB, ((it + 1) << 2) | kp);
    }
    __syncthreads();                             // ER/mask reads done; reuse smem

    // ---- tail: 4-way kp reduction. red reuses erpk4+mlds region (48 KB).
    float* red = (float*)smem;                   // [3kp'][2isub][8f][4r][64]
    if (kp && m == 0) {
        #pragma unroll
        for (int hh = 0; hh < NH; ++hh)
            #pragma unroll
            for (int r = 0; r < 4; ++r)
                sred[(((kp - 1) * 2 + isub) * 16 + hh * 4 + r) * 4 + quad] = sacc[hh][r];
    }
    float v[8][4], inv[4][4];
    #pragma unroll
    for (int hh = 0; hh < NH; ++hh) {
        if (kp) {
            #pragma unroll
            for (int f = 0; f < 8; ++f)
                #pragma unroll
                for (int r = 0; r < 4; ++r)
                    red[((((kp - 1) * 2 + isub) * 8 + f) * 4 + r) * 64 + lane] = acc[f][hh][r];
        }
        __syncthreads();
        if (kp == 0) {
            if (hh == 0) {
                #pragma unroll
                for (int h2 = 0; h2 < NH; ++h2)
                    #pragma unroll
                    for (int r = 0; r < 4; ++r) {
                        float S = sacc[h2][r];
                        #pragma unroll
                        for (int k2 = 0; k2 < 3; ++k2)
                            S += sred[((k2 * 2 + isub) * 16 + h2 * 4 + r) * 4 + quad];
                        inv[h2][r] = (S > 0.f) ? 1.f / S : 0.f;
                    }
            }
            #pragma unroll
            for (int f = 0; f < 8; ++f)
                #pragma unroll
                for (int r = 0; r < 4; ++r) {
                    float tot = acc[f][hh][r];
                    #pragma unroll
                    for (int k2 = 0; k2 < 3; ++k2)
                        tot += red[(((k2 * 2 + isub) * 8 + f) * 4 + r) * 64 + lane];
                    float t2 = tot * inv[hh][r];
                    if (hh == 0) v[f][r] = t2; else v[f][r] += t2;
                }
        }
        __syncthreads();
    }
    if (kp == 0) {
        #pragma unroll
        for (int r = 0; r < 4; ++r) {
            int orow = i0 + isub * 16 + quad * 4 + r;
            #pragma unroll
            for (int f = 0; f < 8; ++f)
                out[((size_t)b * NN + orow) * FOUT + f * 16 + m] =
                    fmaxf(0.25f * v[f][r], 0.f);
        }
    }
}

extern "C" void kernel_launch(void* const* d_in, const int* in_sizes, int n_in,
                              void* d_out, int out_size, void* d_ws, size_t ws_size,
                              hipStream_t stream) {
    const float* h    = (const float*)d_in[0];
    const int* adj    = (const int*)d_in[1];
    const float* Ww   = (const float*)d_in[2];
    const float* Wb   = (const float*)d_in[3];
    const float* attw = (const float*)d_in[4];
    float* out = (float*)d_out;
    char* ws = (char*)d_ws;
    // workspace layout (~3.2 MB)
    unsigned short* Whi = (unsigned short*)(ws);                 // 64 KB
    unsigned short* Wlo = (unsigned short*)(ws + 65536);         // 64 KB
    unsigned short* WhT = (unsigned short*)(ws + 131072);        // 2 MB [b][o][n] bf16
    float2*       ELpair = (float2*)(ws + 2228224);              // 256 KB [bh][i]
    unsigned int* ERpk   = (unsigned int*)(ws + 2490368);        // 128 KB [b][j][h] bf16 pair
    u64*          mask   = (u64*)(ws + 2752512);                 // 512 KB

    k0_prep<<<dim3(128), dim3(256), 0, stream>>>(Ww, Whi, Wlo);
    k1_wh<<<dim3(BB * NN / 16 + NN), dim3(256), 0, stream>>>(h, Whi, Wlo, Wb, attw,
                                                             WhT, ELpair, ERpk,
                                                             adj, mask);
    k2_reg<<<dim3(NN / 32, BB), dim3(512), 0, stream>>>(WhT, ERpk, ELpair,
                                                        mask, out);
}

// Round 23
// 146.060 us; speedup vs baseline: 1.0623x; 1.0623x over previous
//
#include <hip/hip_runtime.h>
#include <stdint.h>

#define BB 4
#define NN 2048
#define FIN 256
#define FOUT 128
#define NH 4
#define NEG_SLOPE 0.2f

typedef short bf16x8 __attribute__((ext_vector_type(8)));
typedef unsigned short u16x8 __attribute__((ext_vector_type(8)));
typedef float f32x4 __attribute__((ext_vector_type(4)));
typedef unsigned long long u64;

__device__ inline float b2f(unsigned short u) {
    union { unsigned int i; float f; } x; x.i = ((unsigned int)u) << 16; return x.f;
}
__device__ inline float asf(unsigned int u) {
    union { unsigned int i; float f; } x; x.i = u; return x.f;
}
__device__ inline unsigned short f2b(float f) {   // fp32 -> bf16 RNE
    union { float f; unsigned int i; } x; x.f = f;
    unsigned int r = x.i + 0x7fffu + ((x.i >> 16) & 1u);
    return (unsigned short)(r >> 16);
}
__device__ inline unsigned short f2b_fast(float f) {  // round-half-up (f >= 0 here)
    union { float f; unsigned int i; } x; x.f = f;
    return (unsigned short)((x.i + 0x8000u) >> 16);
}

// ---------------------------------------------------------------------------
// NOTE (timing model, R5): the harness's workspace poison-fill (~43 µs) runs
// INSIDE the timed window. Controllable budget = dur - 43.
// NOTE (R2): no cross-block fences. NOTE (R10): A built in fragment regs.
// NOTE (R16/R17): ER broadcast needs a BIJECTIVE XOR skew.
// NOTE (R21): at launch_bounds(512,2) the unified VGPR+AGPR budget is 256 and
// v5 sits AT it (128 VGPR + 128 AGPR acc). The R18 B-double-buffer (+64 VGPR)
// spilled: WRITE_SIZE 4->62 MB, k2 44->72 µs. Latency fixes must be
// register-neutral. This version: v5 structure + bf16-packed ER only
// (halves the per-iter ds_read chain, saves transient regs; numerics proven
// in R21's passing run).
// ---------------------------------------------------------------------------

// ---------------------------------------------------------------------------
// k0_prep: W fp32 -> bf16 hi/lo split only (mask pack lives in k1).
// ---------------------------------------------------------------------------
__global__ __launch_bounds__(256) void k0_prep(const float* __restrict__ Ww,
                                               unsigned short* __restrict__ Whi,
                                               unsigned short* __restrict__ Wlo) {
    int idx = blockIdx.x * 256 + threadIdx.x;   // 32768 elems
    float v = Ww[idx];
    unsigned short hb = f2b(v);
    Whi[idx] = hb;
    Wlo[idx] = f2b(v - b2f(hb));
}

// ---------------------------------------------------------------------------
// K1 (MFMA): blocks [0,512): Wh tile + WhT/EL tables + PACKED ER (bf16 pair
// per (j,h): u32 = f2b(exp(eR)) | f2b(exp(.2 eR))<<16).
// blocks [512, 512+NN): adj row -> 32 u64 bitmask words (overlaps compute).
// ---------------------------------------------------------------------------
__global__ __launch_bounds__(256) void k1_wh(
    const float* __restrict__ h, const unsigned short* __restrict__ Whi,
    const unsigned short* __restrict__ Wlo, const float* __restrict__ Wb,
    const float* __restrict__ attw, unsigned short* __restrict__ WhT,
    float2* __restrict__ ELpair, unsigned int* __restrict__ ERpk,
    const int* __restrict__ adj, u64* __restrict__ mask) {
    if (blockIdx.x >= BB * NN / 16) {            // ---- mask-pack blocks
        int row = blockIdx.x - BB * NN / 16;
        int wave = threadIdx.x >> 6, lane = threadIdx.x & 63;
        #pragma unroll
        for (int it = 0; it < 8; ++it) {
            int w = it * 4 + wave;
            int j = w * 64 + lane;
            u64 mm = __ballot(adj[(size_t)row * NN + j] != 0);
            if (lane == 0) mask[row * 32 + w] = mm;
        }
        return;
    }
    __shared__ unsigned short Ahi[16][264];
    __shared__ unsigned short Alo[16][264];
    __shared__ float whs[16][132];
    int t = threadIdx.x;
    int b = blockIdx.x >> 7;
    int n0 = (blockIdx.x & 127) * 16;
    {
        int r = t >> 4, c = (t & 15) * 16;
        const float* hp = h + ((size_t)(b * NN + n0 + r)) * FIN + c;
        u16x8 hi0, hi1, lo0, lo1;
        #pragma unroll
        for (int q = 0; q < 4; ++q) {
            float4 v = *(const float4*)(hp + q * 4);
            float vv[4] = {v.x, v.y, v.z, v.w};
            #pragma unroll
            for (int e = 0; e < 4; ++e) {
                int idx = q * 4 + e;
                unsigned short hb = f2b(vv[e]);
                unsigned short lb = f2b(vv[e] - b2f(hb));
                if (idx < 8) { hi0[idx] = (short)hb; lo0[idx] = (short)lb; }
                else         { hi1[idx - 8] = (short)hb; lo1[idx - 8] = (short)lb; }
            }
        }
        *(u16x8*)&Ahi[r][c] = *(u16x8*)&hi0;
        *(u16x8*)&Ahi[r][c + 8] = *(u16x8*)&hi1;
        *(u16x8*)&Alo[r][c] = *(u16x8*)&lo0;
        *(u16x8*)&Alo[r][c + 8] = *(u16x8*)&lo1;
    }
    __syncthreads();
    int lane = t & 63, wv = t >> 6;
    int m = lane & 15, quad = lane >> 4;
    int o0 = wv * 32;
    f32x4 acc0 = {0.f, 0.f, 0.f, 0.f}, acc1 = {0.f, 0.f, 0.f, 0.f};
    const unsigned short* wh0 = Whi + (size_t)(o0 + m) * FIN;
    const unsigned short* wl0 = Wlo + (size_t)(o0 + m) * FIN;
    const unsigned short* wh1 = Whi + (size_t)(o0 + 16 + m) * FIN;
    const unsigned short* wl1 = Wlo + (size_t)(o0 + 16 + m) * FIN;
    #pragma unroll
    for (int ks = 0; ks < 8; ++ks) {
        int ko = ks * 32 + quad * 8;
        bf16x8 ahi = *(bf16x8*)&Ahi[m][ko];
        bf16x8 alo = *(bf16x8*)&Alo[m][ko];
        bf16x8 bh0 = *(const bf16x8*)(wh0 + ko);
        bf16x8 bl0 = *(const bf16x8*)(wl0 + ko);
        bf16x8 bh1 = *(const bf16x8*)(wh1 + ko);
        bf16x8 bl1 = *(const bf16x8*)(wl1 + ko);
        acc0 = __builtin_amdgcn_mfma_f32_16x16x32_bf16(ahi, bh0, acc0, 0, 0, 0);
        acc0 = __builtin_amdgcn_mfma_f32_16x16x32_bf16(ahi, bl0, acc0, 0, 0, 0);
        acc0 = __builtin_amdgcn_mfma_f32_16x16x32_bf16(alo, bh0, acc0, 0, 0, 0);
        acc1 = __builtin_amdgcn_mfma_f32_16x16x32_bf16(ahi, bh1, acc1, 0, 0, 0);
        acc1 = __builtin_amdgcn_mfma_f32_16x16x32_bf16(ahi, bl1, acc1, 0, 0, 0);
        acc1 = __builtin_amdgcn_mfma_f32_16x16x32_bf16(alo, bh1, acc1, 0, 0, 0);
    }
    float bias0 = Wb[o0 + m], bias1 = Wb[o0 + 16 + m];
    #pragma unroll
    for (int reg = 0; reg < 4; ++reg) {
        int row = quad * 4 + reg;
        whs[row][o0 + m] = acc0[reg] + bias0;
        whs[row][o0 + 16 + m] = acc1[reg] + bias1;
    }
    __syncthreads();
    {   // WhT writer: 2 threads per o, 8 n each
        int o = t >> 1, half = t & 1;
        u16x8 v8;
        #pragma unroll
        for (int r = 0; r < 8; ++r) v8[r] = (short)f2b(whs[half * 8 + r][o]);
        *(u16x8*)(WhT + (size_t)(b * FOUT + o) * NN + n0 + half * 8) = v8;
    }
    {   // e-dots + exp tables
        int outi = t >> 1, half = t & 1;
        int i = outi >> 3, d = outi & 7, hh = d & 3, side = d >> 2;
        const float* arow = attw + hh * (2 * FOUT) + side * FOUT + half * 64;
        float s = 0.f;
        #pragma unroll 8
        for (int k = 0; k < 64; ++k) s = fmaf(whs[i][half * 64 + k], arow[k], s);
        s += __shfl_xor(s, 1);
        if (half == 0) {
            float p = __expf(s), n = __expf(NEG_SLOPE * s);
            if (side == 0) {
                ELpair[(size_t)(b * NH + hh) * NN + n0 + i] = make_float2(p, n);
            } else {
                ERpk[((size_t)b * NN + n0 + i) * NH + hh] =
                    (unsigned)f2b(p) | ((unsigned)f2b(n) << 16);
            }
        }
    }
}

// ---------------------------------------------------------------------------
// K2 v7 = v5 structure (register-neutral) + bf16-packed ER.
// waves = (isub 2) x (kp 4); each wave: 16 i-rows x ALL 128 o x 16 ks-iters.
// Per iter: 8 B-frag loads (single-buffered — R21: no reg headroom for
// prefetch), 8 packed-ER uint4 LDS reads (halved vs v5), A built in regs,
// ones-MFMA denominators. Tail: 4-way kp reduce. grid (NN/32, BB), 512 thr.
// ---------------------------------------------------------------------------
__global__ __launch_bounds__(512, 2) void k2_reg(
    const unsigned short* __restrict__ WhT, const unsigned int* __restrict__ ERpk,
    const float2* __restrict__ ELpair, const u64* __restrict__ mask,
    float* __restrict__ out) {
    __shared__ char smem[49152 + 1536];          // 49.5 KB
    uint4* erpk4 = (uint4*)smem;                 // [2048] XOR-skewed (32 KB)
    u64* mlds = (u64*)(smem + 32768);            // [32][33] padded (8448 B)
    float* sred = (float*)(smem + 49152);        // [3kp'][2isub][4h][4r][4quad]
    int t = threadIdx.x;
    int b = blockIdx.y, i0 = blockIdx.x * 32;
    int lane = t & 63, wv = t >> 6;
    int m = lane & 15, quad = lane >> 4;
    int isub = wv & 1, kp = wv >> 1;             // kp in 0..3

    {   // stage packed ER for this b (bijective XOR-skewed destination)
        const uint4* src = (const uint4*)ERpk + (size_t)b * NN;
        #pragma unroll
        for (int i = 0; i < 4; ++i) {
            int g = t + i * 512;
            erpk4[g ^ (((g >> 3) & 3) << 1)] = src[g];
        }
    }
    {   // stage masks: 32 rows x 32 words, padded stride 33
        #pragma unroll
        for (int i = 0; i < 2; ++i) {
            int idx = t + i * 512;
            int r = idx >> 5, w = idx & 31;
            mlds[r * 33 + w] = mask[(size_t)(i0 + r) * 32 + w];
        }
    }
    int irow = i0 + isub * 16 + m;               // this lane's A row
    float elp[NH], eln[NH];
    #pragma unroll
    for (int hh = 0; hh < NH; ++hh) {
        float2 e2 = ELpair[(size_t)(b * NH + hh) * NN + irow];
        elp[hh] = e2.x; eln[hh] = e2.y;
    }
    __syncthreads();

    bf16x8 ones;
    #pragma unroll
    for (int e = 0; e < 8; ++e) ones[e] = (short)0x3F80;   // bf16 1.0

    const unsigned short* bp[8];
    #pragma unroll
    for (int f = 0; f < 8; ++f)
        bp[f] = WhT + (size_t)(b * FOUT + f * 16 + m) * NN + kp * 32 + quad * 8;

    f32x4 acc[8][NH];                            // [o-frag f][head h]
    f32x4 sacc[NH];                              // [head h] denominator
    #pragma unroll
    for (int f = 0; f < 8; ++f)
        #pragma unroll
        for (int hh = 0; hh < NH; ++hh) acc[f][hh] = (f32x4){0.f, 0.f, 0.f, 0.f};
    #pragma unroll
    for (int hh = 0; hh < NH; ++hh) sacc[hh] = (f32x4){0.f, 0.f, 0.f, 0.f};

    int mr = isub * 16 + m;                      // local mask row
    int qs = quad << 1;                          // XOR skew for reads

    for (int it = 0; it < 16; ++it) {
        int ks = (it << 2) | kp;
        int jb = ks * 32 + quad * 8;             // lane's 8-j window
        bf16x8 bfr[8];
        #pragma unroll
        for (int f = 0; f < 8; ++f) bfr[f] = *(const bf16x8*)(bp[f]);
        u64 w64 = mlds[mr * 33 + (ks >> 1)];
        unsigned mb = (unsigned)(w64 >> (((ks & 1) << 5) + (quad << 3))) & 0xFFu;
        bf16x8 af0, af1, af2, af3;
        #pragma unroll
        for (int e = 0; e < 8; ++e) {
            uint4 er = erpk4[(jb + e) ^ qs];     // 4 heads packed, 1 LDS read
            bool bit = (mb >> e) & 1u;
            float w0 = fmaxf(elp[0] * asf(er.x << 16), eln[0] * asf(er.x & 0xFFFF0000u));
            float w1 = fmaxf(elp[1] * asf(er.y << 16), eln[1] * asf(er.y & 0xFFFF0000u));
            float w2 = fmaxf(elp[2] * asf(er.z << 16), eln[2] * asf(er.z & 0xFFFF0000u));
            float w3 = fmaxf(elp[3] * asf(er.w << 16), eln[3] * asf(er.w & 0xFFFF0000u));
            af0[e] = bit ? (short)f2b_fast(w0) : (short)0;
            af1[e] = bit ? (short)f2b_fast(w1) : (short)0;
            af2[e] = bit ? (short)f2b_fast(w2) : (short)0;
            af3[e] = bit ? (short)f2b_fast(w3) : (short)0;
        }
        sacc[0] = __builtin_amdgcn_mfma_f32_16x16x32_bf16(af0, ones, sacc[0], 0, 0, 0);
        sacc[1] = __builtin_amdgcn_mfma_f32_16x16x32_bf16(af1, ones, sacc[1], 0, 0, 0);
        sacc[2] = __builtin_amdgcn_mfma_f32_16x16x32_bf16(af2, ones, sacc[2], 0, 0, 0);
        sacc[3] = __builtin_amdgcn_mfma_f32_16x16x32_bf16(af3, ones, sacc[3], 0, 0, 0);
        #pragma unroll
        for (int f = 0; f < 8; ++f) {
            acc[f][0] = __builtin_amdgcn_mfma_f32_16x16x32_bf16(af0, bfr[f], acc[f][0], 0, 0, 0);
            acc[f][1] = __builtin_amdgcn_mfma_f32_16x16x32_bf16(af1, bfr[f], acc[f][1], 0, 0, 0);
            acc[f][2] = __builtin_amdgcn_mfma_f32_16x16x32_bf16(af2, bfr[f], acc[f][2], 0, 0, 0);
            acc[f][3] = __builtin_amdgcn_mfma_f32_16x16x32_bf16(af3, bfr[f], acc[f][3], 0, 0, 0);
        }
        #pragma unroll
        for (int f = 0; f < 8; ++f) bp[f] += 128;
    }
    __syncthreads();                             // ER/mask reads done; reuse smem

    // ---- tail: 4-way kp reduction. red reuses erpk4+mlds region (48 KB).
    float* red = (float*)smem;                   // [3kp'][2isub][8f][4r][64]
    if (kp && m == 0) {
        #pragma unroll
        for (int hh = 0; hh < NH; ++hh)
            #pragma unroll
            for (int r = 0; r < 4; ++r)
                sred[(((kp - 1) * 2 + isub) * 16 + hh * 4 + r) * 4 + quad] = sacc[hh][r];
    }
    float v[8][4], inv[4][4];
    #pragma unroll
    for (int hh = 0; hh < NH; ++hh) {
        if (kp) {
            #pragma unroll
            for (int f = 0; f < 8; ++f)
                #pragma unroll
                for (int r = 0; r < 4; ++r)
                    red[((((kp - 1) * 2 + isub) * 8 + f) * 4 + r) * 64 + lane] = acc[f][hh][r];
        }
        __syncthreads();
        if (kp == 0) {
            if (hh == 0) {
                #pragma unroll
                for (int h2 = 0; h2 < NH; ++h2)
                    #pragma unroll
                    for (int r = 0; r < 4; ++r) {
                        float S = sacc[h2][r];
                        #pragma unroll
                        for (int k2 = 0; k2 < 3; ++k2)
                            S += sred[((k2 * 2 + isub) * 16 + h2 * 4 + r) * 4 + quad];
                        inv[h2][r] = (S > 0.f) ? 1.f / S : 0.f;
                    }
            }
            #pragma unroll
            for (int f = 0; f < 8; ++f)
                #pragma unroll
                for (int r = 0; r < 4; ++r) {
                    float tot = acc[f][hh][r];
                    #pragma unroll
                    for (int k2 = 0; k2 < 3; ++k2)
                        tot += red[(((k2 * 2 + isub) * 8 + f) * 4 + r) * 64 + lane];
                    float t2 = tot * inv[hh][r];
                    if (hh == 0) v[f][r] = t2; else v[f][r] += t2;
                }
        }
        __syncthreads();
    }
    if (kp == 0) {
        #pragma unroll
        for (int r = 0; r < 4; ++r) {
            int orow = i0 + isub * 16 + quad * 4 + r;
            #pragma unroll
            for (int f = 0; f < 8; ++f)
                out[((size_t)b * NN + orow) * FOUT + f * 16 + m] =
                    fmaxf(0.25f * v[f][r], 0.f);
        }
    }
}

extern "C" void kernel_launch(void* const* d_in, const int* in_sizes, int n_in,
                              void* d_out, int out_size, void* d_ws, size_t ws_size,
                              hipStream_t stream) {
    const float* h    = (const float*)d_in[0];
    const int* adj    = (const int*)d_in[1];
    const float* Ww   = (const float*)d_in[2];
    const float* Wb   = (const float*)d_in[3];
    const float* attw = (const float*)d_in[4];
    float* out = (float*)d_out;
    char* ws = (char*)d_ws;
    // workspace layout (~3.2 MB)
    unsigned short* Whi = (unsigned short*)(ws);                 // 64 KB
    unsigned short* Wlo = (unsigned short*)(ws + 65536);         // 64 KB
    unsigned short* WhT = (unsigned short*)(ws + 131072);        // 2 MB [b][o][n] bf16
    float2*       ELpair = (float2*)(ws + 2228224);              // 256 KB [bh][i]
    unsigned int* ERpk   = (unsigned int*)(ws + 2490368);        // 128 KB [b][j][h] bf16 pair
    u64*          mask   = (u64*)(ws + 2752512);                 // 512 KB

    k0_prep<<<dim3(128), dim3(256), 0, stream>>>(Ww, Whi, Wlo);
    k1_wh<<<dim3(BB * NN / 16 + NN), dim3(256), 0, stream>>>(h, Whi, Wlo, Wb, attw,
                                                             WhT, ELpair, ERpk,
                                                             adj, mask);
    k2_reg<<<dim3(NN / 32, BB), dim3(512), 0, stream>>>(WhT, ERpk, ELpair,
                                                        mask, out);
}

// Round 24
// 125.173 us; speedup vs baseline: 1.2395x; 1.1669x over previous
//
#include <hip/hip_runtime.h>
#include <stdint.h>

#define BB 4
#define NN 2048
#define FIN 256
#define FOUT 128
#define NH 4
#define NEG_SLOPE 0.2f

typedef short bf16x8 __attribute__((ext_vector_type(8)));
typedef unsigned short u16x8 __attribute__((ext_vector_type(8)));
typedef float f32x4 __attribute__((ext_vector_type(4)));
typedef unsigned long long u64;

__device__ inline float b2f(unsigned short u) {
    union { unsigned int i; float f; } x; x.i = ((unsigned int)u) << 16; return x.f;
}
__device__ inline unsigned short f2b(float f) {   // fp32 -> bf16 RNE
    union { float f; unsigned int i; } x; x.f = f;
    unsigned int r = x.i + 0x7fffu + ((x.i >> 16) & 1u);
    return (unsigned short)(r >> 16);
}
__device__ inline unsigned short f2b_fast(float f) {  // round-half-up (f >= 0 here)
    union { float f; unsigned int i; } x; x.f = f;
    return (unsigned short)((x.i + 0x8000u) >> 16);
}

// ---------------------------------------------------------------------------
// NOTE (timing model, R5): the harness's workspace poison-fill (~43 µs) runs
// INSIDE the timed window. Controllable budget = dur - 43.
// NOTE (R2): no cross-block fences (device-scope threadfence cost ~120 µs).
// NOTE (R10): A built in fragment registers (LDS A-tiles = 1KB read/MFMA).
// NOTE (R16/R17): ER broadcast needs a BIJECTIVE XOR skew.
// NOTE (R21): unified VGPR+AGPR budget 256/lane at (512,2); v5 sits AT it.
// B-double-buffer (+64 VGPR) spilled (WRITE 4->62MB, 44->72µs).
// NOTE (R23): bf16-packed ER regressed 44->61µs — the removed LDS reads were
// parallel (latency already overlapped) while the unpack added DEPENDENT
// VALU per element. In this latency-bound regime only serial-chain cuts or
// occupancy help. This is the exact R18 measured-best kernel (125.4 µs).
// ---------------------------------------------------------------------------

// ---------------------------------------------------------------------------
// k0_prep: W fp32 -> bf16 hi/lo split only (mask pack lives in k1).
// ---------------------------------------------------------------------------
__global__ __launch_bounds__(256) void k0_prep(const float* __restrict__ Ww,
                                               unsigned short* __restrict__ Whi,
                                               unsigned short* __restrict__ Wlo) {
    int idx = blockIdx.x * 256 + threadIdx.x;   // 32768 elems
    float v = Ww[idx];
    unsigned short hb = f2b(v);
    Whi[idx] = hb;
    Wlo[idx] = f2b(v - b2f(hb));
}

// ---------------------------------------------------------------------------
// K1 (MFMA): blocks [0,512): Wh tile + WhT/EL/ER tables.
// blocks [512, 512+NN): adj row -> 32 u64 bitmask words (overlaps Wh compute).
// ---------------------------------------------------------------------------
__global__ __launch_bounds__(256) void k1_wh(
    const float* __restrict__ h, const unsigned short* __restrict__ Whi,
    const unsigned short* __restrict__ Wlo, const float* __restrict__ Wb,
    const float* __restrict__ attw, unsigned short* __restrict__ WhT,
    float2* __restrict__ ELpair, float2* __restrict__ ERf,
    const int* __restrict__ adj, u64* __restrict__ mask) {
    if (blockIdx.x >= BB * NN / 16) {            // ---- mask-pack blocks
        int row = blockIdx.x - BB * NN / 16;
        int wave = threadIdx.x >> 6, lane = threadIdx.x & 63;
        #pragma unroll
        for (int it = 0; it < 8; ++it) {
            int w = it * 4 + wave;
            int j = w * 64 + lane;
            u64 mm = __ballot(adj[(size_t)row * NN + j] != 0);
            if (lane == 0) mask[row * 32 + w] = mm;
        }
        return;
    }
    __shared__ unsigned short Ahi[16][264];
    __shared__ unsigned short Alo[16][264];
    __shared__ float whs[16][132];
    int t = threadIdx.x;
    int b = blockIdx.x >> 7;
    int n0 = (blockIdx.x & 127) * 16;
    {
        int r = t >> 4, c = (t & 15) * 16;
        const float* hp = h + ((size_t)(b * NN + n0 + r)) * FIN + c;
        u16x8 hi0, hi1, lo0, lo1;
        #pragma unroll
        for (int q = 0; q < 4; ++q) {
            float4 v = *(const float4*)(hp + q * 4);
            float vv[4] = {v.x, v.y, v.z, v.w};
            #pragma unroll
            for (int e = 0; e < 4; ++e) {
                int idx = q * 4 + e;
                unsigned short hb = f2b(vv[e]);
                unsigned short lb = f2b(vv[e] - b2f(hb));
                if (idx < 8) { hi0[idx] = (short)hb; lo0[idx] = (short)lb; }
                else         { hi1[idx - 8] = (short)hb; lo1[idx - 8] = (short)lb; }
            }
        }
        *(u16x8*)&Ahi[r][c] = *(u16x8*)&hi0;
        *(u16x8*)&Ahi[r][c + 8] = *(u16x8*)&hi1;
        *(u16x8*)&Alo[r][c] = *(u16x8*)&lo0;
        *(u16x8*)&Alo[r][c + 8] = *(u16x8*)&lo1;
    }
    __syncthreads();
    int lane = t & 63, wv = t >> 6;
    int m = lane & 15, quad = lane >> 4;
    int o0 = wv * 32;
    f32x4 acc0 = {0.f, 0.f, 0.f, 0.f}, acc1 = {0.f, 0.f, 0.f, 0.f};
    const unsigned short* wh0 = Whi + (size_t)(o0 + m) * FIN;
    const unsigned short* wl0 = Wlo + (size_t)(o0 + m) * FIN;
    const unsigned short* wh1 = Whi + (size_t)(o0 + 16 + m) * FIN;
    const unsigned short* wl1 = Wlo + (size_t)(o0 + 16 + m) * FIN;
    #pragma unroll
    for (int ks = 0; ks < 8; ++ks) {
        int ko = ks * 32 + quad * 8;
        bf16x8 ahi = *(bf16x8*)&Ahi[m][ko];
        bf16x8 alo = *(bf16x8*)&Alo[m][ko];
        bf16x8 bh0 = *(const bf16x8*)(wh0 + ko);
        bf16x8 bl0 = *(const bf16x8*)(wl0 + ko);
        bf16x8 bh1 = *(const bf16x8*)(wh1 + ko);
        bf16x8 bl1 = *(const bf16x8*)(wl1 + ko);
        acc0 = __builtin_amdgcn_mfma_f32_16x16x32_bf16(ahi, bh0, acc0, 0, 0, 0);
        acc0 = __builtin_amdgcn_mfma_f32_16x16x32_bf16(ahi, bl0, acc0, 0, 0, 0);
        acc0 = __builtin_amdgcn_mfma_f32_16x16x32_bf16(alo, bh0, acc0, 0, 0, 0);
        acc1 = __builtin_amdgcn_mfma_f32_16x16x32_bf16(ahi, bh1, acc1, 0, 0, 0);
        acc1 = __builtin_amdgcn_mfma_f32_16x16x32_bf16(ahi, bl1, acc1, 0, 0, 0);
        acc1 = __builtin_amdgcn_mfma_f32_16x16x32_bf16(alo, bh1, acc1, 0, 0, 0);
    }
    float bias0 = Wb[o0 + m], bias1 = Wb[o0 + 16 + m];
    #pragma unroll
    for (int reg = 0; reg < 4; ++reg) {
        int row = quad * 4 + reg;
        whs[row][o0 + m] = acc0[reg] + bias0;
        whs[row][o0 + 16 + m] = acc1[reg] + bias1;
    }
    __syncthreads();
    {   // WhT writer: 2 threads per o, 8 n each
        int o = t >> 1, half = t & 1;
        u16x8 v8;
        #pragma unroll
        for (int r = 0; r < 8; ++r) v8[r] = (short)f2b(whs[half * 8 + r][o]);
        *(u16x8*)(WhT + (size_t)(b * FOUT + o) * NN + n0 + half * 8) = v8;
    }
    {   // e-dots + exp tables
        int outi = t >> 1, half = t & 1;
        int i = outi >> 3, d = outi & 7, hh = d & 3, side = d >> 2;
        const float* arow = attw + hh * (2 * FOUT) + side * FOUT + half * 64;
        float s = 0.f;
        #pragma unroll 8
        for (int k = 0; k < 64; ++k) s = fmaf(whs[i][half * 64 + k], arow[k], s);
        s += __shfl_xor(s, 1);
        if (half == 0) {
            float p = __expf(s), n = __expf(NEG_SLOPE * s);
            if (side == 0) {
                ELpair[(size_t)(b * NH + hh) * NN + n0 + i] = make_float2(p, n);
            } else {
                ERf[((size_t)b * NN + n0 + i) * NH + hh] = make_float2(p, n);
            }
        }
    }
}

// ---------------------------------------------------------------------------
// K2 v5 (measured best: 44 µs, conflicts 0, no spill): register-fragment A
// build; waves = (isub 2) x (kp 4); each wave owns 16 i-rows x ALL 128 o
// (8 B-frags) x ks = kp, kp+4, ... (16 iters). Zero A-build duplication;
// ERf LDS uses BIJECTIVE XOR skew: store g ^ (((g>>4)&3)<<1), read
// (gb+e*2) ^ (quad<<1) -> quads on disjoint bank groups. No main-loop
// barriers. Denominators via ones-MFMA (D-row layout). Tail: 4-way kp
// reduce through reused LDS. grid (NN/32, BB) = 256 blocks x 512 thr.
// ---------------------------------------------------------------------------
__global__ __launch_bounds__(512, 2) void k2_reg(
    const unsigned short* __restrict__ WhT, const float2* __restrict__ ERf,
    const float2* __restrict__ ELpair, const u64* __restrict__ mask,
    float* __restrict__ out) {
    __shared__ char smem[65600 + 8448 + 1536];   // 73.8 KB
    float4* erf4 = (float4*)smem;                // XOR-skewed [4096] float4
    u64* mlds = (u64*)(smem + 65600);            // [32][33] padded
    float* sred = (float*)(smem + 65600 + 8448); // [3kp'][2isub][4h][4r][4quad]
    int t = threadIdx.x;
    int b = blockIdx.y, i0 = blockIdx.x * 32;
    int lane = t & 63, wv = t >> 6;
    int m = lane & 15, quad = lane >> 4;
    int isub = wv & 1, kp = wv >> 1;             // kp in 0..3

    {   // stage ERf for this b (bijective XOR-skewed destination)
        const float4* src = (const float4*)(ERf + (size_t)b * NN * NH);
        #pragma unroll
        for (int i = 0; i < 8; ++i) {
            int g = t + i * 512;
            erf4[g ^ (((g >> 4) & 3) << 1)] = src[g];
        }
    }
    {   // stage masks: 32 rows x 32 words, padded stride 33
        #pragma unroll
        for (int i = 0; i < 2; ++i) {
            int idx = t + i * 512;
            int r = idx >> 5, w = idx & 31;
            mlds[r * 33 + w] = mask[(size_t)(i0 + r) * 32 + w];
        }
    }
    int irow = i0 + isub * 16 + m;               // this lane's A row
    float elp[NH], eln[NH];
    #pragma unroll
    for (int hh = 0; hh < NH; ++hh) {
        float2 e2 = ELpair[(size_t)(b * NH + hh) * NN + irow];
        elp[hh] = e2.x; eln[hh] = e2.y;
    }
    __syncthreads();

    bf16x8 ones;
    #pragma unroll
    for (int e = 0; e < 8; ++e) ones[e] = (short)0x3F80;   // bf16 1.0

    const unsigned short* bp[8];
    #pragma unroll
    for (int f = 0; f < 8; ++f)
        bp[f] = WhT + (size_t)(b * FOUT + f * 16 + m) * NN + kp * 32 + quad * 8;

    f32x4 acc[8][NH];                            // [o-frag f][head h]
    f32x4 sacc[NH];                              // [head h] denominator
    #pragma unroll
    for (int f = 0; f < 8; ++f)
        #pragma unroll
        for (int hh = 0; hh < NH; ++hh) acc[f][hh] = (f32x4){0.f, 0.f, 0.f, 0.f};
    #pragma unroll
    for (int hh = 0; hh < NH; ++hh) sacc[hh] = (f32x4){0.f, 0.f, 0.f, 0.f};

    int mr = isub * 16 + m;                      // local mask row
    int qs = quad << 1;                          // XOR skew for reads

    for (int it = 0; it < 16; ++it) {
        int ks = (it << 2) | kp;
        int jb = ks * 32 + quad * 8;             // lane's 8-j window
        bf16x8 bfr[8];
        #pragma unroll
        for (int f = 0; f < 8; ++f) bfr[f] = *(const bf16x8*)(bp[f]);
        u64 w64 = mlds[mr * 33 + (ks >> 1)];
        unsigned mb = (unsigned)(w64 >> (((ks & 1) << 5) + (quad << 3))) & 0xFFu;
        int gb = jb * 2;                         // unskewed float4 base (mod16==0)
        bf16x8 af0, af1, af2, af3;
        #pragma unroll
        for (int e = 0; e < 8; ++e) {
            int a0 = (gb + e * 2) ^ qs;          // (g>>4)&3 == quad here
            float4 e0 = erf4[a0];                // h0p h0n h1p h1n
            float4 e1 = erf4[a0 + 1];            // h2p h2n h3p h3n
            bool bit = (mb >> e) & 1u;
            float w0 = fmaxf(elp[0] * e0.x, eln[0] * e0.y);
            float w1 = fmaxf(elp[1] * e0.z, eln[1] * e0.w);
            float w2 = fmaxf(elp[2] * e1.x, eln[2] * e1.y);
            float w3 = fmaxf(elp[3] * e1.z, eln[3] * e1.w);
            af0[e] = bit ? (short)f2b_fast(w0) : (short)0;
            af1[e] = bit ? (short)f2b_fast(w1) : (short)0;
            af2[e] = bit ? (short)f2b_fast(w2) : (short)0;
            af3[e] = bit ? (short)f2b_fast(w3) : (short)0;
        }
        sacc[0] = __builtin_amdgcn_mfma_f32_16x16x32_bf16(af0, ones, sacc[0], 0, 0, 0);
        sacc[1] = __builtin_amdgcn_mfma_f32_16x16x32_bf16(af1, ones, sacc[1], 0, 0, 0);
        sacc[2] = __builtin_amdgcn_mfma_f32_16x16x32_bf16(af2, ones, sacc[2], 0, 0, 0);
        sacc[3] = __builtin_amdgcn_mfma_f32_16x16x32_bf16(af3, ones, sacc[3], 0, 0, 0);
        #pragma unroll
        for (int f = 0; f < 8; ++f) {
            acc[f][0] = __builtin_amdgcn_mfma_f32_16x16x32_bf16(af0, bfr[f], acc[f][0], 0, 0, 0);
            acc[f][1] = __builtin_amdgcn_mfma_f32_16x16x32_bf16(af1, bfr[f], acc[f][1], 0, 0, 0);
            acc[f][2] = __builtin_amdgcn_mfma_f32_16x16x32_bf16(af2, bfr[f], acc[f][2], 0, 0, 0);
            acc[f][3] = __builtin_amdgcn_mfma_f32_16x16x32_bf16(af3, bfr[f], acc[f][3], 0, 0, 0);
        }
        #pragma unroll
        for (int f = 0; f < 8; ++f) bp[f] += 128;
    }
    __syncthreads();                             // ERf reads done; reuse smem

    // ---- tail: 4-way kp reduction. red reuses erf4 region (48 KB).
    float* red = (float*)smem;                   // [3kp'][2isub][8f][4r][64]
    if (kp && m == 0) {
        #pragma unroll
        for (int hh = 0; hh < NH; ++hh)
            #pragma unroll
            for (int r = 0; r < 4; ++r)
                sred[(((kp - 1) * 2 + isub) * 16 + hh * 4 + r) * 4 + quad] = sacc[hh][r];
    }
    float v[8][4], inv[4][4];
    #pragma unroll
    for (int hh = 0; hh < NH; ++hh) {
        if (kp) {
            #pragma unroll
            for (int f = 0; f < 8; ++f)
                #pragma unroll
                for (int r = 0; r < 4; ++r)
                    red[((((kp - 1) * 2 + isub) * 8 + f) * 4 + r) * 64 + lane] = acc[f][hh][r];
        }
        __syncthreads();
        if (kp == 0) {
            if (hh == 0) {
                #pragma unroll
                for (int h2 = 0; h2 < NH; ++h2)
                    #pragma unroll
                    for (int r = 0; r < 4; ++r) {
                        float S = sacc[h2][r];
                        #pragma unroll
                        for (int k2 = 0; k2 < 3; ++k2)
                            S += sred[((k2 * 2 + isub) * 16 + h2 * 4 + r) * 4 + quad];
                        inv[h2][r] = (S > 0.f) ? 1.f / S : 0.f;
                    }
            }
            #pragma unroll
            for (int f = 0; f < 8; ++f)
                #pragma unroll
                for (int r = 0; r < 4; ++r) {
                    float tot = acc[f][hh][r];
                    #pragma unroll
                    for (int k2 = 0; k2 < 3; ++k2)
                        tot += red[(((k2 * 2 + isub) * 8 + f) * 4 + r) * 64 + lane];
                    float t2 = tot * inv[hh][r];
                    if (hh == 0) v[f][r] = t2; else v[f][r] += t2;
                }
        }
        __syncthreads();
    }
    if (kp == 0) {
        #pragma unroll
        for (int r = 0; r < 4; ++r) {
            int orow = i0 + isub * 16 + quad * 4 + r;
            #pragma unroll
            for (int f = 0; f < 8; ++f)
                out[((size_t)b * NN + orow) * FOUT + f * 16 + m] =
                    fmaxf(0.25f * v[f][r], 0.f);
        }
    }
}

extern "C" void kernel_launch(void* const* d_in, const int* in_sizes, int n_in,
                              void* d_out, int out_size, void* d_ws, size_t ws_size,
                              hipStream_t stream) {
    const float* h    = (const float*)d_in[0];
    const int* adj    = (const int*)d_in[1];
    const float* Ww   = (const float*)d_in[2];
    const float* Wb   = (const float*)d_in[3];
    const float* attw = (const float*)d_in[4];
    float* out = (float*)d_out;
    char* ws = (char*)d_ws;
    // workspace layout (~3.3 MB)
    unsigned short* Whi = (unsigned short*)(ws);                 // 64 KB
    unsigned short* Wlo = (unsigned short*)(ws + 65536);         // 64 KB
    unsigned short* WhT = (unsigned short*)(ws + 131072);        // 2 MB [b][o][n] bf16
    float2*       ELpair = (float2*)(ws + 2228224);              // 256 KB [bh][i]
    float2*       ERf    = (float2*)(ws + 2490368);              // 256 KB [b][j][h] f32 pair
    u64*          mask   = (u64*)(ws + 2752512);                 // 512 KB

    k0_prep<<<dim3(128), dim3(256), 0, stream>>>(Ww, Whi, Wlo);
    k1_wh<<<dim3(BB * NN / 16 + NN), dim3(256), 0, stream>>>(h, Whi, Wlo, Wb, attw,
                                                             WhT, ELpair, ERf,
                                                             adj, mask);
    k2_reg<<<dim3(NN / 32, BB), dim3(512), 0, stream>>>(WhT, ERf, ELpair,
                                                        mask, out);
}